// Round 3
// baseline (670.013 us; speedup 1.0000x reference)
//
#include <hip/hip_runtime.h>
#include <hip/hip_bf16.h>

#define HID 2048
#define NH 20
#define QR 768
#define KVR 512
#define DN 192
#define DR 64
#define DV 256
#define HD 256          // HEAD_DIM = DN + DR
#define S_LEN 2048
#define HKV 448         // DN + DV
#define KV_N (NH * HKV) // 8960
#define Q_N (NH * HD)   // 5120
#define O_N (NH * DV)   // 5120
#define KVA_N (KVR + DR) // 576
#define KVAP 640         // padded kv_a rows

typedef short bf16x8 __attribute__((ext_vector_type(8)));
typedef float f32x4 __attribute__((ext_vector_type(4)));

__device__ inline short f2bs(float f) {
  __hip_bfloat16 h = __float2bfloat16(f);
  return *reinterpret_cast<short*>(&h);
}
__device__ inline float bs2f(short s) {
  __hip_bfloat16 h = *reinterpret_cast<__hip_bfloat16*>(&s);
  return __bfloat162float(h);
}

// async global->LDS, 16B per lane. LDS dest must be linear in lane order.
__device__ inline void gload16(const void* g, void* l) {
  __builtin_amdgcn_global_load_lds((const __attribute__((address_space(1))) void*)g,
                                   (__attribute__((address_space(3))) void*)l, 16, 0, 0);
}

// ---------------- fp32 -> bf16 convert ----------------
__global__ void f2b_kernel(const float* __restrict__ in, short* __restrict__ out, size_t n) {
  size_t i = (size_t)blockIdx.x * blockDim.x + threadIdx.x;
  size_t stride = (size_t)gridDim.x * blockDim.x;
  for (; i < n; i += stride) out[i] = f2bs(in[i]);
}

// ---------------- big GEMM: 128x128 tile, BK=64, global_load_lds + XOR swizzle ----------------
// C[M][N] = A[M][K] @ B[N][K]^T, all dims: M%128==0, N%128==0, K%64==0
template <int OUT_BF16>
__global__ __launch_bounds__(256) void gemm128(const short* __restrict__ A,
                                               const short* __restrict__ B,
                                               void* __restrict__ Cp,
                                               int M, int N, int K) {
  __shared__ alignas(16) short As[128 * 64];
  __shared__ alignas(16) short Bs[128 * 64];
  int tid = threadIdx.x;
  int w = tid >> 6, l = tid & 63;
  int lr = l & 15, lg = l >> 4;
  int wr = w >> 1, wc = w & 1;
  int row0 = blockIdx.y * 128, col0 = blockIdx.x * 128;
  f32x4 acc[4][4] = {};
  for (int k0 = 0; k0 < K; k0 += 64) {
    if (k0) __syncthreads();
#pragma unroll
    for (int p = 0; p < 4; ++p) {
      int c = p * 256 + tid;      // 16B chunk id, 1024 total
      int row = c >> 3;           // 8 chunks per 128B row
      int bofs = (c & 7) * 16;
      int sb = bofs ^ ((row & 7) << 4);
      gload16((const char*)A + ((size_t)(row0 + row) * K + k0) * 2 + sb, (char*)As + c * 16);
      gload16((const char*)B + ((size_t)(col0 + row) * K + k0) * 2 + sb, (char*)Bs + c * 16);
    }
    __syncthreads();
    bf16x8 af[4][2], bf[4][2];
#pragma unroll
    for (int m = 0; m < 4; ++m)
#pragma unroll
      for (int kk = 0; kk < 2; ++kk) {
        int ra = wr * 64 + m * 16 + lr;
        int rb = wc * 64 + m * 16 + lr;
        int cb = kk * 64 + lg * 16;
        af[m][kk] = *(const bf16x8*)((const char*)As + ra * 128 + (cb ^ ((ra & 7) << 4)));
        bf[m][kk] = *(const bf16x8*)((const char*)Bs + rb * 128 + (cb ^ ((rb & 7) << 4)));
      }
#pragma unroll
    for (int m = 0; m < 4; ++m)
#pragma unroll
      for (int n = 0; n < 4; ++n) {
        acc[m][n] = __builtin_amdgcn_mfma_f32_16x16x32_bf16(af[m][0], bf[n][0], acc[m][n], 0, 0, 0);
        acc[m][n] = __builtin_amdgcn_mfma_f32_16x16x32_bf16(af[m][1], bf[n][1], acc[m][n], 0, 0, 0);
      }
  }
#pragma unroll
  for (int m = 0; m < 4; ++m)
#pragma unroll
    for (int n = 0; n < 4; ++n)
#pragma unroll
      for (int r = 0; r < 4; ++r) {
        int row = row0 + wr * 64 + m * 16 + lg * 4 + r;
        int col = col0 + wc * 64 + n * 16 + lr;
        if (OUT_BF16)
          ((short*)Cp)[(size_t)row * N + col] = f2bs(acc[m][n][r]);
        else
          ((float*)Cp)[(size_t)row * N + col] = acc[m][n][r];
      }
}

// ---------------- rmsnorm (fp32 in, bf16 out) ----------------
__global__ __launch_bounds__(256) void rmsnorm_kernel(const float* __restrict__ in,
                                                      const float* __restrict__ w,
                                                      short* __restrict__ out,
                                                      int N, int in_stride, int out_stride) {
  int row = blockIdx.x;
  const float* x = in + (size_t)row * in_stride;
  float ss = 0.f;
  for (int i = threadIdx.x; i < N; i += 256) { float v = x[i]; ss += v * v; }
#pragma unroll
  for (int off = 32; off >= 1; off >>= 1) ss += __shfl_down(ss, off);
  __shared__ float red[4];
  if ((threadIdx.x & 63) == 0) red[threadIdx.x >> 6] = ss;
  __syncthreads();
  float tot = red[0] + red[1] + red[2] + red[3];
  float sc = rsqrtf(tot / (float)N + 1e-5f);
  short* o = out + (size_t)row * out_stride;
  for (int i = threadIdx.x; i < N; i += 256) o[i] = f2bs(x[i] * sc * w[i]);
}

// ---------------- rope tables ----------------
__global__ void rope_table_kernel(const int* __restrict__ pos, float* __restrict__ ct,
                                  float* __restrict__ st) {
  int s = blockIdx.x * blockDim.x + threadIdx.x;
  if (s >= S_LEN) return;
  double p = (double)pos[s];
  for (int d = 0; d < 32; ++d) {
    double invf = exp(-((double)(2 * d) / 64.0) * log(1.0e6));
    double a = p * invf;
    ct[s * 32 + d] = (float)cos(a);
    st[s * 32 + d] = (float)sin(a);
  }
}

// ---------------- rope applied in-place to q's rope slice ----------------
__global__ void rope_q_kernel(short* __restrict__ q, const float* __restrict__ ct,
                              const float* __restrict__ st) {
  int idx = blockIdx.x * blockDim.x + threadIdx.x;
  if (idx >= S_LEN * NH) return;
  int s = idx / NH, h = idx % NH;
  short* p = q + (size_t)s * Q_N + h * HD + DN;
  float x[64];
#pragma unroll
  for (int i = 0; i < 64; ++i) x[i] = bs2f(p[i]);
  const float* c = ct + s * 32;
  const float* sn = st + s * 32;
#pragma unroll
  for (int d = 0; d < 32; ++d) {
    float x1 = x[2 * d], x2 = x[2 * d + 1];
    p[d] = f2bs(x1 * c[d] - x2 * sn[d]);
    p[32 + d] = f2bs(x1 * sn[d] + x2 * c[d]);
  }
}

// ---------------- rope for shared k_rope (reads padded kv_c) ----------------
__global__ void rope_k_kernel(const float* __restrict__ kv_c, const float* __restrict__ ct,
                              const float* __restrict__ st, short* __restrict__ kr) {
  int s = blockIdx.x * blockDim.x + threadIdx.x;
  if (s >= S_LEN) return;
  const float* x = kv_c + (size_t)s * KVAP + KVR;
  const float* c = ct + s * 32;
  const float* sn = st + s * 32;
  short* o = kr + s * 64;
#pragma unroll
  for (int d = 0; d < 32; ++d) {
    float x1 = x[2 * d], x2 = x[2 * d + 1];
    o[d] = f2bs(x1 * c[d] - x2 * sn[d]);
    o[32 + d] = f2bs(x1 * sn[d] + x2 * c[d]);
  }
}

// ---------------- build Kc[h][s][256] = k_nope ‖ roped k_rope ----------------
__global__ void kc_build(const short* __restrict__ kvx, const short* __restrict__ kr,
                         short* __restrict__ kc) {
  int idx = blockIdx.x * 256 + threadIdx.x;  // NH*S*32 chunks of 8 elems
  int h = idx >> 16;                          // S*32 = 65536
  int r = idx & 65535;
  int s = r >> 5, c = r & 31;
  const short* src = (c < 24) ? kvx + (size_t)s * KV_N + h * HKV + c * 8
                              : kr + (size_t)s * 64 + (c - 24) * 8;
  *(bf16x8*)(kc + ((size_t)h * S_LEN + s) * HD + c * 8) = *(const bf16x8*)src;
}

// ---------------- transpose V: Vt[h][d][s] from kvx[s][h*448+192+d] ----------------
__global__ __launch_bounds__(256) void vtrans(const short* __restrict__ kvx,
                                              short* __restrict__ vtg) {
  __shared__ short tile[64][65];
  int s0 = blockIdx.x * 64, d0 = blockIdx.y * 64, h = blockIdx.z;
  int tid = threadIdx.x;
#pragma unroll
  for (int p = 0; p < 2; ++p) {
    int s = p * 32 + (tid >> 3), dc = (tid & 7) * 8;
    bf16x8 v = *(const bf16x8*)(kvx + (size_t)(s0 + s) * KV_N + h * HKV + DN + d0 + dc);
#pragma unroll
    for (int j = 0; j < 8; ++j) tile[s][dc + j] = v[j];
  }
  __syncthreads();
#pragma unroll
  for (int p = 0; p < 2; ++p) {
    int d = p * 32 + (tid >> 3), sc = (tid & 7) * 8;
    bf16x8 o;
#pragma unroll
    for (int j = 0; j < 8; ++j) o[j] = tile[sc + j][d];
    *(bf16x8*)(vtg + ((size_t)h * DV + d0 + d) * S_LEN + s0 + sc) = o;
  }
}

// ---------------- fused flash attention v3 ----------------
// grid = 640 blocks (XCD-swizzled -> (h, qblk)); 256 thr (4 waves x 16 q-rows); KV-block 32
// K tile: double-buffered LDS via global_load_lds (swizzled source), prefetch 1 tile ahead.
// V tile: global->reg prefetch, late LDS write (single buffer, 2 barriers/iter).
// Softmax: defer-max (THR=8) skips acc rescale; row-sum via MFMA vs ones-fragment.
__global__ __launch_bounds__(256) void attn3(const short* __restrict__ q,
                                             const short* __restrict__ kc,
                                             const short* __restrict__ vtg,
                                             short* __restrict__ out) {
  __shared__ alignas(16) short ks[2][32 * 256];  // 2 x 16KB
  __shared__ alignas(16) short vt[256 * 40];     // 20KB, vt[d][key], stride 40
  __shared__ alignas(16) short pb[4][16][32];    // 4KB per-wave P tile
  int bid = blockIdx.x;
  int swz = (bid & 7) * 80 + (bid >> 3);         // XCD-contiguous remap (640 = 8*80)
  int h = swz >> 5, qblk = swz & 31;
  int tid = threadIdx.x;
  int w = tid >> 6, l = tid & 63;
  int lr = l & 15, lg = l >> 4;

  const char* kch = (const char*)(kc + (size_t)h * S_LEN * HD);
  const short* vth = vtg + (size_t)h * DV * S_LEN;

  // Q frags, pre-scaled by 2^-4 (exact in bf16)
  int qrow = qblk * 64 + w * 16 + lr;
  const short* qbase = q + (size_t)qrow * Q_N + h * HD;
  bf16x8 qf[8];
#pragma unroll
  for (int kk = 0; kk < 8; ++kk) {
    bf16x8 v = *(const bf16x8*)(qbase + kk * 32 + lg * 8);
#pragma unroll
    for (int j = 0; j < 8; ++j) v[j] = f2bs(bs2f(v[j]) * 0.0625f);
    qf[kk] = v;
  }

  bf16x8 ones;
#pragma unroll
  for (int j = 0; j < 8; ++j) ones[j] = (short)0x3F80;

  f32x4 acc[16] = {};
  f32x4 accL = {};
  float m[4] = {-3e38f, -3e38f, -3e38f, -3e38f};

  bf16x8 vreg[4];
  auto stage_k = [&](int buf, int key0) {
#pragma unroll
    for (int p = 0; p < 4; ++p) {
      int c = p * 256 + tid;
      int row = c >> 5;
      int sb = ((c & 31) * 16) ^ ((row & 7) << 4);
      gload16(kch + (size_t)(key0 + row) * 512 + sb, (char*)ks[buf] + c * 16);
    }
  };
  auto load_v = [&](int key0) {
#pragma unroll
    for (int p = 0; p < 4; ++p) {
      int c = p * 256 + tid;
      int vr = c >> 2, so = c & 3;
      vreg[p] = *(const bf16x8*)(vth + (size_t)vr * S_LEN + key0 + so * 8);
    }
  };
  auto write_v = [&]() {
#pragma unroll
    for (int p = 0; p < 4; ++p) {
      int c = p * 256 + tid;
      int vr = c >> 2, so = c & 3;
      *(bf16x8*)&vt[vr * 40 + so * 8] = vreg[p];
    }
  };

  // prologue: stage tile 0
  stage_k(0, 0);
  load_v(0);
  asm volatile("s_waitcnt vmcnt(0)" ::: "memory");
  write_v();
  __syncthreads();

  for (int kb = 0; kb < S_LEN / 32; ++kb) {
    int cur = kb & 1;
    bool pre = (kb + 1) < S_LEN / 32;
    if (pre) {
      stage_k(cur ^ 1, (kb + 1) * 32);  // async K prefetch into other buffer
      load_v((kb + 1) * 32);            // V prefetch into registers
    }
    // QK^T: 16 q-rows x 32 keys per wave
    f32x4 s0 = {}, s1 = {};
#pragma unroll
    for (int kk = 0; kk < 8; ++kk) {
      int cb = kk * 64 + lg * 16;
      int r0 = lr, r1 = 16 + lr;
      bf16x8 k0 = *(const bf16x8*)((const char*)ks[cur] + r0 * 512 + (cb ^ ((r0 & 7) << 4)));
      bf16x8 k1 = *(const bf16x8*)((const char*)ks[cur] + r1 * 512 + (cb ^ ((r1 & 7) << 4)));
      s0 = __builtin_amdgcn_mfma_f32_16x16x32_bf16(qf[kk], k0, s0, 0, 0, 0);
      s1 = __builtin_amdgcn_mfma_f32_16x16x32_bf16(qf[kk], k1, s1, 0, 0, 0);
    }
    // tile max per row + defer-max check
    float mx[4];
    bool grow = false;
#pragma unroll
    for (int r = 0; r < 4; ++r) {
      float v = fmaxf(s0[r], s1[r]);
#pragma unroll
      for (int off = 1; off < 16; off <<= 1) v = fmaxf(v, __shfl_xor(v, off));
      mx[r] = v;
      grow = grow || (v > m[r] + 8.f);
    }
    if (__any((int)grow)) {
      float co[4];
#pragma unroll
      for (int r = 0; r < 4; ++r) {
        float mn = fmaxf(m[r], mx[r]);
        co[r] = __expf(m[r] - mn);
        m[r] = mn;
      }
#pragma unroll
      for (int t = 0; t < 16; ++t)
#pragma unroll
        for (int r = 0; r < 4; ++r) acc[t][r] *= co[r];
#pragma unroll
      for (int r = 0; r < 4; ++r) accL[r] *= co[r];
    }
#pragma unroll
    for (int r = 0; r < 4; ++r) {
      float p0 = __expf(s0[r] - m[r]);
      float p1 = __expf(s1[r] - m[r]);
      pb[w][lg * 4 + r][lr] = f2bs(p0);
      pb[w][lg * 4 + r][16 + lr] = f2bs(p1);
    }
    asm volatile("s_waitcnt lgkmcnt(0)" ::: "memory");
    bf16x8 pf = *(const bf16x8*)&pb[w][lr][lg * 8];
    accL = __builtin_amdgcn_mfma_f32_16x16x32_bf16(pf, ones, accL, 0, 0, 0);
#pragma unroll
    for (int t = 0; t < 16; ++t) {
      bf16x8 vf = *(const bf16x8*)&vt[(t * 16 + lr) * 40 + lg * 8];
      acc[t] = __builtin_amdgcn_mfma_f32_16x16x32_bf16(pf, vf, acc[t], 0, 0, 0);
    }
    __syncthreads();  // all waves done reading vt
    if (pre) {
      asm volatile("s_waitcnt vmcnt(0)" ::: "memory");  // vreg + K gloads landed
      write_v();
    }
    __syncthreads();  // vt + ks[cur^1] ready for next iter
  }

  float inv[4];
#pragma unroll
  for (int r = 0; r < 4; ++r) inv[r] = 1.f / accL[r];
#pragma unroll
  for (int t = 0; t < 16; ++t)
#pragma unroll
    for (int r = 0; r < 4; ++r) {
      int row = qblk * 64 + w * 16 + lg * 4 + r;
      int col = h * DV + t * 16 + lr;
      out[(size_t)row * O_N + col] = f2bs(acc[t][r] * inv[r]);
    }
}

extern "C" void kernel_launch(void* const* d_in, const int* in_sizes, int n_in,
                              void* d_out, int out_size, void* d_ws, size_t ws_size,
                              hipStream_t stream) {
  const float* x       = (const float*)d_in[0];
  const int*   pos     = (const int*)d_in[1];
  const float* q_a_w   = (const float*)d_in[2];
  const float* q_b_w   = (const float*)d_in[3];
  const float* kv_a_w  = (const float*)d_in[4];
  const float* kv_b_w  = (const float*)d_in[5];
  const float* o_w     = (const float*)d_in[6];
  const float* q_a_ln  = (const float*)d_in[7];
  const float* kv_a_ln = (const float*)d_in[8];
  float* out = (float*)d_out;

  char* p = (char*)d_ws;
  auto alloc = [&](size_t bytes) {
    char* r = p;
    p += (bytes + 255) & ~(size_t)255;
    return r;
  };
  short* xb    = (short*)alloc((size_t)S_LEN * HID * 2);
  short* qaw   = (short*)alloc((size_t)QR * HID * 2);
  short* qbw   = (short*)alloc((size_t)Q_N * QR * 2);
  short* kvawp = (short*)alloc((size_t)KVAP * HID * 2);   // padded to 640 rows
  short* kvbw  = (short*)alloc((size_t)KV_N * KVR * 2);
  short* ow    = (short*)alloc((size_t)HID * O_N * 2);
  float* q_a   = (float*)alloc((size_t)S_LEN * QR * 4);
  short* q_ln  = (short*)alloc((size_t)S_LEN * QR * 2);
  short* qbuf  = (short*)alloc((size_t)S_LEN * Q_N * 2);
  float* kv_cp = (float*)alloc((size_t)S_LEN * KVAP * 4); // padded stride 640
  short* kv_ln = (short*)alloc((size_t)S_LEN * KVR * 2);
  short* kvx   = (short*)alloc((size_t)S_LEN * KV_N * 2);
  short* kr    = (short*)alloc((size_t)S_LEN * 64 * 2);
  float* ct    = (float*)alloc((size_t)S_LEN * 32 * 4);
  float* st    = (float*)alloc((size_t)S_LEN * 32 * 4);
  short* ao    = (short*)alloc((size_t)S_LEN * O_N * 2);
  short* kcb   = (short*)alloc((size_t)NH * S_LEN * HD * 2);
  short* vtg   = (short*)alloc((size_t)NH * DV * S_LEN * 2);
  (void)ws_size; (void)n_in; (void)in_sizes; (void)out_size;

  auto cvt = [&](const float* in, short* o, size_t n) {
    size_t blocks = (n + 255) / 256;
    if (blocks > 2048) blocks = 2048;
    f2b_kernel<<<dim3((unsigned)blocks), dim3(256), 0, stream>>>(in, o, n);
  };
  cvt(x, xb, (size_t)S_LEN * HID);
  cvt(q_a_w, qaw, (size_t)QR * HID);
  cvt(q_b_w, qbw, (size_t)Q_N * QR);
  cvt(kv_a_w, kvawp, (size_t)KVA_N * HID);
  hipMemsetAsync(kvawp + (size_t)KVA_N * HID, 0, (size_t)(KVAP - KVA_N) * HID * 2, stream);
  cvt(kv_b_w, kvbw, (size_t)KV_N * KVR);
  cvt(o_w, ow, (size_t)HID * O_N);

  dim3 blk(256);
  // q_a = x @ q_a_w^T ; kv_c = x @ kv_a_w^T (padded N=640), fp32 out
  gemm128<0><<<dim3(QR / 128, S_LEN / 128), blk, 0, stream>>>(xb, qaw, q_a, S_LEN, QR, HID);
  gemm128<0><<<dim3(KVAP / 128, S_LEN / 128), blk, 0, stream>>>(xb, kvawp, kv_cp, S_LEN, KVAP, HID);
  // rmsnorms -> bf16
  rmsnorm_kernel<<<dim3(S_LEN), blk, 0, stream>>>(q_a, q_a_ln, q_ln, QR, QR, QR);
  rmsnorm_kernel<<<dim3(S_LEN), blk, 0, stream>>>(kv_cp, kv_a_ln, kv_ln, KVR, KVAP, KVR);
  // up-projections -> bf16
  gemm128<1><<<dim3(Q_N / 128, S_LEN / 128), blk, 0, stream>>>(q_ln, qbw, qbuf, S_LEN, Q_N, QR);
  gemm128<1><<<dim3(KV_N / 128, S_LEN / 128), blk, 0, stream>>>(kv_ln, kvbw, kvx, S_LEN, KV_N, KVR);
  // rope
  rope_table_kernel<<<dim3(S_LEN / 256), blk, 0, stream>>>(pos, ct, st);
  rope_q_kernel<<<dim3((S_LEN * NH + 255) / 256), blk, 0, stream>>>(qbuf, ct, st);
  rope_k_kernel<<<dim3(S_LEN / 256), blk, 0, stream>>>(kv_cp, ct, st, kr);
  // rearrange K and transpose V into per-head contiguous layouts
  kc_build<<<dim3(NH * S_LEN * 32 / 256), blk, 0, stream>>>(kvx, kr, kcb);
  vtrans<<<dim3(S_LEN / 64, DV / 64, NH), blk, 0, stream>>>(kvx, vtg);
  // fused attention
  attn3<<<dim3(NH * S_LEN / 64), blk, 0, stream>>>(qbuf, kcb, vtg, ao);
  // output projection (fp32 out)
  gemm128<0><<<dim3(HID / 128, S_LEN / 128), blk, 0, stream>>>(ao, ow, out, S_LEN, HID, O_N);
}

// Round 5
// 656.252 us; speedup vs baseline: 1.0210x; 1.0210x over previous
//
#include <hip/hip_runtime.h>
#include <hip/hip_bf16.h>

#define HID 2048
#define NH 20
#define QR 768
#define KVR 512
#define DN 192
#define DR 64
#define DV 256
#define HD 256          // HEAD_DIM = DN + DR
#define S_LEN 2048
#define HKV 448         // DN + DV
#define KV_N (NH * HKV) // 8960
#define Q_N (NH * HD)   // 5120
#define O_N (NH * DV)   // 5120
#define KVA_N (KVR + DR) // 576
#define KVAP 640         // padded kv_a rows
#define QKVA (QR + KVAP) // 1408 fused a-proj cols

typedef short bf16x8 __attribute__((ext_vector_type(8)));
typedef float f32x4 __attribute__((ext_vector_type(4)));

__device__ inline short f2bs(float f) {
  __hip_bfloat16 h = __float2bfloat16(f);
  return *reinterpret_cast<short*>(&h);
}
__device__ inline float bs2f(short s) {
  __hip_bfloat16 h = *reinterpret_cast<__hip_bfloat16*>(&s);
  return __bfloat162float(h);
}

__device__ inline void gload16(const void* g, void* l) {
  __builtin_amdgcn_global_load_lds((const __attribute__((address_space(1))) void*)g,
                                   (__attribute__((address_space(3))) void*)l, 16, 0, 0);
}

#define WAIT_LGKM0() asm volatile("s_waitcnt lgkmcnt(0)" ::: "memory")
#define WAIT_VM0() asm volatile("s_waitcnt vmcnt(0)" ::: "memory")

// ---------------- fp32 -> bf16 convert ----------------
__global__ void f2b_kernel(const float* __restrict__ in, short* __restrict__ out, size_t n) {
  size_t i = (size_t)blockIdx.x * blockDim.x + threadIdx.x;
  size_t stride = (size_t)gridDim.x * blockDim.x;
  for (; i < n; i += stride) out[i] = f2bs(in[i]);
}

// ---------------- big GEMM: 128x128 tile, BK=64, global_load_lds + XOR swizzle ----------------
template <int OUT_BF16>
__global__ __launch_bounds__(256) void gemm128(const short* __restrict__ A,
                                               const short* __restrict__ B,
                                               void* __restrict__ Cp,
                                               int M, int N, int K) {
  __shared__ alignas(16) short As[128 * 64];
  __shared__ alignas(16) short Bs[128 * 64];
  int tid = threadIdx.x;
  int w = tid >> 6, l = tid & 63;
  int lr = l & 15, lg = l >> 4;
  int wr = w >> 1, wc = w & 1;
  int row0 = blockIdx.y * 128, col0 = blockIdx.x * 128;
  f32x4 acc[4][4] = {};
  for (int k0 = 0; k0 < K; k0 += 64) {
    if (k0) __syncthreads();
#pragma unroll
    for (int p = 0; p < 4; ++p) {
      int c = p * 256 + tid;
      int row = c >> 3;
      int sb = ((c & 7) * 16) ^ ((row & 7) << 4);
      gload16((const char*)A + ((size_t)(row0 + row) * K + k0) * 2 + sb, (char*)As + c * 16);
      gload16((const char*)B + ((size_t)(col0 + row) * K + k0) * 2 + sb, (char*)Bs + c * 16);
    }
    __syncthreads();
    bf16x8 af[4][2], bf[4][2];
#pragma unroll
    for (int m = 0; m < 4; ++m)
#pragma unroll
      for (int kk = 0; kk < 2; ++kk) {
        int ra = wr * 64 + m * 16 + lr;
        int rb = wc * 64 + m * 16 + lr;
        int cb = kk * 64 + lg * 16;
        af[m][kk] = *(const bf16x8*)((const char*)As + ra * 128 + (cb ^ ((ra & 7) << 4)));
        bf[m][kk] = *(const bf16x8*)((const char*)Bs + rb * 128 + (cb ^ ((rb & 7) << 4)));
      }
#pragma unroll
    for (int m = 0; m < 4; ++m)
#pragma unroll
      for (int n = 0; n < 4; ++n) {
        acc[m][n] = __builtin_amdgcn_mfma_f32_16x16x32_bf16(af[m][0], bf[n][0], acc[m][n], 0, 0, 0);
        acc[m][n] = __builtin_amdgcn_mfma_f32_16x16x32_bf16(af[m][1], bf[n][1], acc[m][n], 0, 0, 0);
      }
  }
#pragma unroll
  for (int m = 0; m < 4; ++m)
#pragma unroll
    for (int n = 0; n < 4; ++n)
#pragma unroll
      for (int r = 0; r < 4; ++r) {
        int row = row0 + wr * 64 + m * 16 + lg * 4 + r;
        int col = col0 + wc * 64 + n * 16 + lr;
        if (OUT_BF16)
          ((short*)Cp)[(size_t)row * N + col] = f2bs(acc[m][n][r]);
        else
          ((float*)Cp)[(size_t)row * N + col] = acc[m][n][r];
      }
}

// ---------------- medium GEMM: 64x128 tile (for wide-short shapes) ----------------
__global__ __launch_bounds__(256) void gemm64(const short* __restrict__ A,
                                              const short* __restrict__ B,
                                              float* __restrict__ C,
                                              int M, int N, int K) {
  __shared__ alignas(16) short As[64 * 64];    // 8KB
  __shared__ alignas(16) short Bs[128 * 64];   // 16KB
  int tid = threadIdx.x;
  int w = tid >> 6, l = tid & 63;
  int lr = l & 15, lg = l >> 4;
  int wr = w >> 1, wc = w & 1;
  int row0 = blockIdx.y * 64, col0 = blockIdx.x * 128;
  f32x4 acc[2][4] = {};
  for (int k0 = 0; k0 < K; k0 += 64) {
    if (k0) __syncthreads();
#pragma unroll
    for (int p = 0; p < 2; ++p) {
      int c = p * 256 + tid;
      int row = c >> 3;
      int sb = ((c & 7) * 16) ^ ((row & 7) << 4);
      gload16((const char*)A + ((size_t)(row0 + row) * K + k0) * 2 + sb, (char*)As + c * 16);
    }
#pragma unroll
    for (int p = 0; p < 4; ++p) {
      int c = p * 256 + tid;
      int row = c >> 3;
      int sb = ((c & 7) * 16) ^ ((row & 7) << 4);
      gload16((const char*)B + ((size_t)(col0 + row) * K + k0) * 2 + sb, (char*)Bs + c * 16);
    }
    __syncthreads();
    bf16x8 af[2][2], bf[4][2];
#pragma unroll
    for (int m = 0; m < 2; ++m)
#pragma unroll
      for (int kk = 0; kk < 2; ++kk) {
        int ra = wr * 32 + m * 16 + lr;
        int cb = kk * 64 + lg * 16;
        af[m][kk] = *(const bf16x8*)((const char*)As + ra * 128 + (cb ^ ((ra & 7) << 4)));
      }
#pragma unroll
    for (int n = 0; n < 4; ++n)
#pragma unroll
      for (int kk = 0; kk < 2; ++kk) {
        int rb = wc * 64 + n * 16 + lr;
        int cb = kk * 64 + lg * 16;
        bf[n][kk] = *(const bf16x8*)((const char*)Bs + rb * 128 + (cb ^ ((rb & 7) << 4)));
      }
#pragma unroll
    for (int m = 0; m < 2; ++m)
#pragma unroll
      for (int n = 0; n < 4; ++n) {
        acc[m][n] = __builtin_amdgcn_mfma_f32_16x16x32_bf16(af[m][0], bf[n][0], acc[m][n], 0, 0, 0);
        acc[m][n] = __builtin_amdgcn_mfma_f32_16x16x32_bf16(af[m][1], bf[n][1], acc[m][n], 0, 0, 0);
      }
  }
#pragma unroll
  for (int m = 0; m < 2; ++m)
#pragma unroll
    for (int n = 0; n < 4; ++n)
#pragma unroll
      for (int r = 0; r < 4; ++r) {
        int row = row0 + wr * 32 + m * 16 + lg * 4 + r;
        int col = col0 + wc * 64 + n * 16 + lr;
        C[(size_t)row * N + col] = acc[m][n][r];
      }
}

// ---------------- rmsnorm (fp32 in, bf16 out) ----------------
__global__ __launch_bounds__(256) void rmsnorm_kernel(const float* __restrict__ in,
                                                      const float* __restrict__ w,
                                                      short* __restrict__ out,
                                                      int N, int in_stride, int out_stride) {
  int row = blockIdx.x;
  const float* x = in + (size_t)row * in_stride;
  float ss = 0.f;
  for (int i = threadIdx.x; i < N; i += 256) { float v = x[i]; ss += v * v; }
#pragma unroll
  for (int off = 32; off >= 1; off >>= 1) ss += __shfl_down(ss, off);
  __shared__ float red[4];
  if ((threadIdx.x & 63) == 0) red[threadIdx.x >> 6] = ss;
  __syncthreads();
  float tot = red[0] + red[1] + red[2] + red[3];
  float sc = rsqrtf(tot / (float)N + 1e-5f);
  short* o = out + (size_t)row * out_stride;
  for (int i = threadIdx.x; i < N; i += 256) o[i] = f2bs(x[i] * sc * w[i]);
}

// ---------------- rope tables ----------------
__global__ void rope_table_kernel(const int* __restrict__ pos, float* __restrict__ ct,
                                  float* __restrict__ st) {
  int s = blockIdx.x * blockDim.x + threadIdx.x;
  if (s >= S_LEN) return;
  double p = (double)pos[s];
  for (int d = 0; d < 32; ++d) {
    double invf = exp(-((double)(2 * d) / 64.0) * log(1.0e6));
    double a = p * invf;
    ct[s * 32 + d] = (float)cos(a);
    st[s * 32 + d] = (float)sin(a);
  }
}

// ---------------- rope applied in-place to q's rope slice ----------------
__global__ void rope_q_kernel(short* __restrict__ q, const float* __restrict__ ct,
                              const float* __restrict__ st) {
  int idx = blockIdx.x * blockDim.x + threadIdx.x;
  if (idx >= S_LEN * NH) return;
  int s = idx / NH, h = idx % NH;
  short* p = q + (size_t)s * Q_N + h * HD + DN;
  float x[64];
#pragma unroll
  for (int i = 0; i < 64; ++i) x[i] = bs2f(p[i]);
  const float* c = ct + s * 32;
  const float* sn = st + s * 32;
#pragma unroll
  for (int d = 0; d < 32; ++d) {
    float x1 = x[2 * d], x2 = x[2 * d + 1];
    p[d] = f2bs(x1 * c[d] - x2 * sn[d]);
    p[32 + d] = f2bs(x1 * sn[d] + x2 * c[d]);
  }
}

// ---------------- rope for shared k_rope (reads fused qkv buffer) ----------------
__global__ void rope_k_kernel(const float* __restrict__ base, const float* __restrict__ ct,
                              const float* __restrict__ st, short* __restrict__ kr) {
  int s = blockIdx.x * blockDim.x + threadIdx.x;
  if (s >= S_LEN) return;
  const float* x = base + (size_t)s * QKVA;
  const float* c = ct + s * 32;
  const float* sn = st + s * 32;
  short* o = kr + s * 64;
#pragma unroll
  for (int d = 0; d < 32; ++d) {
    float x1 = x[2 * d], x2 = x[2 * d + 1];
    o[d] = f2bs(x1 * c[d] - x2 * sn[d]);
    o[32 + d] = f2bs(x1 * sn[d] + x2 * c[d]);
  }
}

// ---------------- build Kc[h][s][256] = k_nope ‖ roped k_rope ----------------
__global__ void kc_build(const short* __restrict__ kvx, const short* __restrict__ kr,
                         short* __restrict__ kc) {
  int idx = blockIdx.x * 256 + threadIdx.x;
  int h = idx >> 16;
  int r = idx & 65535;
  int s = r >> 5, c = r & 31;
  const short* src = (c < 24) ? kvx + (size_t)s * KV_N + h * HKV + c * 8
                              : kr + (size_t)s * 64 + (c - 24) * 8;
  *(bf16x8*)(kc + ((size_t)h * S_LEN + s) * HD + c * 8) = *(const bf16x8*)src;
}

// ---------------- transpose V: Vt[h][d][s] ----------------
__global__ __launch_bounds__(256) void vtrans(const short* __restrict__ kvx,
                                              short* __restrict__ vtg) {
  __shared__ short tile[64][65];
  int s0 = blockIdx.x * 64, d0 = blockIdx.y * 64, h = blockIdx.z;
  int tid = threadIdx.x;
#pragma unroll
  for (int p = 0; p < 2; ++p) {
    int s = p * 32 + (tid >> 3), dc = (tid & 7) * 8;
    bf16x8 v = *(const bf16x8*)(kvx + (size_t)(s0 + s) * KV_N + h * HKV + DN + d0 + dc);
#pragma unroll
    for (int j = 0; j < 8; ++j) tile[s][dc + j] = v[j];
  }
  __syncthreads();
#pragma unroll
  for (int p = 0; p < 2; ++p) {
    int d = p * 32 + (tid >> 3), sc = (tid & 7) * 8;
    bf16x8 o;
#pragma unroll
    for (int j = 0; j < 8; ++j) o[j] = tile[sc + j][d];
    *(bf16x8*)(vtg + ((size_t)h * DV + d0 + d) * S_LEN + s0 + sc) = o;
  }
}

// ---------------- fused flash attention v4b ----------------
// grid = 640 (XCD-swizzled); 256 thr; KVBLK=32; LDS 53KB -> 3 blocks/CU
// K dbuf via gload_lds (swizzled source); V single swizzled buf (2-bit key!),
// reg-staged late-write; raw s_barrier + one full vm drain per iter; setprio on MFMA.
__global__ __launch_bounds__(256) void attn4(const short* __restrict__ q,
                                             const short* __restrict__ kc,
                                             const short* __restrict__ vtg,
                                             short* __restrict__ out) {
  __shared__ alignas(16) short ks[2][32 * 256];  // 32KB
  __shared__ alignas(16) short vt[256 * 32];     // 16KB, row=vdim, 64B rows, 2-bit XOR swizzle
  __shared__ alignas(16) short pb[4][16][40];    // 5KB padded P tiles
  int bid = blockIdx.x;
  int swz = (bid & 7) * 80 + (bid >> 3);
  int h = swz >> 5, qblk = swz & 31;
  int tid = threadIdx.x;
  int w = tid >> 6, l = tid & 63;
  int lr = l & 15, lg = l >> 4;

  const char* kch = (const char*)(kc + (size_t)h * S_LEN * HD);
  const short* vth = vtg + (size_t)h * DV * S_LEN;

  int qrow = qblk * 64 + w * 16 + lr;
  const short* qbase = q + (size_t)qrow * Q_N + h * HD;
  bf16x8 qf[8];
#pragma unroll
  for (int kk = 0; kk < 8; ++kk) {
    bf16x8 v = *(const bf16x8*)(qbase + kk * 32 + lg * 8);
#pragma unroll
    for (int j = 0; j < 8; ++j) v[j] = f2bs(bs2f(v[j]) * 0.0625f);
    qf[kk] = v;
  }

  bf16x8 ones;
#pragma unroll
  for (int j = 0; j < 8; ++j) ones[j] = (short)0x3F80;

  f32x4 acc[16] = {};
  f32x4 accL = {};
  float m[4] = {-3e38f, -3e38f, -3e38f, -3e38f};

  bf16x8 vreg[4];
  auto stage_k = [&](int buf, int key0) {
#pragma unroll
    for (int p = 0; p < 4; ++p) {
      int c = p * 256 + tid;
      int row = c >> 5;
      int sb = ((c & 31) * 16) ^ ((row & 7) << 4);
      gload16(kch + (size_t)(key0 + row) * 512 + sb, (char*)ks[buf] + c * 16);
    }
  };
  auto load_v = [&](int key0) {
#pragma unroll
    for (int p = 0; p < 4; ++p) {
      int c = p * 256 + tid;
      int vr = c >> 2, so = c & 3;
      vreg[p] = *(const bf16x8*)(vth + (size_t)vr * S_LEN + key0 + so * 8);
    }
  };
  auto write_v = [&]() {
#pragma unroll
    for (int p = 0; p < 4; ++p) {
      int c = p * 256 + tid;
      int vr = c >> 2, so = c & 3;
      *(bf16x8*)((char*)vt + vr * 64 + ((so * 16) ^ ((vr & 3) << 4))) = vreg[p];
    }
  };

  // prologue: tile 0
  load_v(0);
  stage_k(0, 0);
  WAIT_VM0();
  write_v();
  WAIT_LGKM0();
  __builtin_amdgcn_s_barrier();

  for (int kb = 0; kb < S_LEN / 32; ++kb) {
    int cur = kb & 1;
    bool pre = (kb + 1) < S_LEN / 32;
    if (pre) {
      load_v((kb + 1) * 32);
      stage_k(cur ^ 1, (kb + 1) * 32);
    }
    __builtin_amdgcn_sched_barrier(0);
    // QK^T
    f32x4 s0 = {}, s1 = {};
    __builtin_amdgcn_s_setprio(1);
#pragma unroll
    for (int kk = 0; kk < 8; ++kk) {
      int cb = kk * 64 + lg * 16;
      int sw = (lr & 7) << 4;
      bf16x8 k0 = *(const bf16x8*)((const char*)ks[cur] + lr * 512 + (cb ^ sw));
      bf16x8 k1 = *(const bf16x8*)((const char*)ks[cur] + (16 + lr) * 512 + (cb ^ sw));
      s0 = __builtin_amdgcn_mfma_f32_16x16x32_bf16(qf[kk], k0, s0, 0, 0, 0);
      s1 = __builtin_amdgcn_mfma_f32_16x16x32_bf16(qf[kk], k1, s1, 0, 0, 0);
    }
    __builtin_amdgcn_s_setprio(0);
    // online softmax, defer-max THR=8
    float mx[4];
    bool grow = false;
#pragma unroll
    for (int r = 0; r < 4; ++r) {
      float v = fmaxf(s0[r], s1[r]);
#pragma unroll
      for (int off = 1; off < 16; off <<= 1) v = fmaxf(v, __shfl_xor(v, off));
      mx[r] = v;
      grow = grow || (v > m[r] + 8.f);
    }
    if (__any((int)grow)) {
      float co[4];
#pragma unroll
      for (int r = 0; r < 4; ++r) {
        float mn = fmaxf(m[r], mx[r]);
        co[r] = __expf(m[r] - mn);
        m[r] = mn;
      }
#pragma unroll
      for (int t = 0; t < 16; ++t)
#pragma unroll
        for (int r = 0; r < 4; ++r) acc[t][r] *= co[r];
#pragma unroll
      for (int r = 0; r < 4; ++r) accL[r] *= co[r];
    }
#pragma unroll
    for (int r = 0; r < 4; ++r) {
      float p0 = __expf(s0[r] - m[r]);
      float p1 = __expf(s1[r] - m[r]);
      pb[w][lg * 4 + r][lr] = f2bs(p0);
      pb[w][lg * 4 + r][16 + lr] = f2bs(p1);
    }
    WAIT_LGKM0();  // pb writes visible within wave
    __builtin_amdgcn_sched_barrier(0);
    bf16x8 pf = *(const bf16x8*)&pb[w][lr][lg * 8];
    __builtin_amdgcn_s_setprio(1);
    accL = __builtin_amdgcn_mfma_f32_16x16x32_bf16(pf, ones, accL, 0, 0, 0);
#pragma unroll
    for (int t = 0; t < 16; ++t) {
      int row = t * 16 + lr;
      bf16x8 vf = *(const bf16x8*)((const char*)vt + row * 64 + ((lg * 16) ^ ((lr & 3) << 4)));
      acc[t] = __builtin_amdgcn_mfma_f32_16x16x32_bf16(pf, vf, acc[t], 0, 0, 0);
    }
    __builtin_amdgcn_s_setprio(0);
    WAIT_LGKM0();                     // this wave's LDS reads retired
    __builtin_amdgcn_s_barrier();     // all waves done reading vt/ks[cur]
    if (pre) {
      WAIT_VM0();                     // V regs + own K[t+1] chunks landed
      write_v();
      WAIT_LGKM0();
    }
    __builtin_amdgcn_s_barrier();     // vt + everyone's ks[cur^1] ready
  }

  float inv[4];
#pragma unroll
  for (int r = 0; r < 4; ++r) inv[r] = 1.f / accL[r];
#pragma unroll
  for (int t = 0; t < 16; ++t)
#pragma unroll
    for (int r = 0; r < 4; ++r) {
      int row = qblk * 64 + w * 16 + lg * 4 + r;
      int col = h * DV + t * 16 + lr;
      out[(size_t)row * O_N + col] = f2bs(acc[t][r] * inv[r]);
    }
}

extern "C" void kernel_launch(void* const* d_in, const int* in_sizes, int n_in,
                              void* d_out, int out_size, void* d_ws, size_t ws_size,
                              hipStream_t stream) {
  const float* x       = (const float*)d_in[0];
  const int*   pos     = (const int*)d_in[1];
  const float* q_a_w   = (const float*)d_in[2];
  const float* q_b_w   = (const float*)d_in[3];
  const float* kv_a_w  = (const float*)d_in[4];
  const float* kv_b_w  = (const float*)d_in[5];
  const float* o_w     = (const float*)d_in[6];
  const float* q_a_ln  = (const float*)d_in[7];
  const float* kv_a_ln = (const float*)d_in[8];
  float* out = (float*)d_out;

  char* p = (char*)d_ws;
  auto alloc = [&](size_t bytes) {
    char* r = p;
    p += (bytes + 255) & ~(size_t)255;
    return r;
  };
  short* xb    = (short*)alloc((size_t)S_LEN * HID * 2);
  short* wcat  = (short*)alloc((size_t)QKVA * HID * 2);   // q_a_w ‖ kv_a_w(padded)
  short* qbw   = (short*)alloc((size_t)Q_N * QR * 2);
  short* kvbw  = (short*)alloc((size_t)KV_N * KVR * 2);
  short* ow    = (short*)alloc((size_t)HID * O_N * 2);
  float* qkv   = (float*)alloc((size_t)S_LEN * QKVA * 4); // fused a-proj out
  short* q_ln  = (short*)alloc((size_t)S_LEN * QR * 2);
  short* qbuf  = (short*)alloc((size_t)S_LEN * Q_N * 2);
  short* kv_ln = (short*)alloc((size_t)S_LEN * KVR * 2);
  short* kvx   = (short*)alloc((size_t)S_LEN * KV_N * 2);
  short* kr    = (short*)alloc((size_t)S_LEN * 64 * 2);
  float* ct    = (float*)alloc((size_t)S_LEN * 32 * 4);
  float* st    = (float*)alloc((size_t)S_LEN * 32 * 4);
  short* ao    = (short*)alloc((size_t)S_LEN * O_N * 2);
  short* kcb   = (short*)alloc((size_t)NH * S_LEN * HD * 2);
  short* vtg   = (short*)alloc((size_t)NH * DV * S_LEN * 2);
  (void)ws_size; (void)n_in; (void)in_sizes; (void)out_size;

  auto cvt = [&](const float* in, short* o, size_t n) {
    size_t blocks = (n + 255) / 256;
    if (blocks > 2048) blocks = 2048;
    f2b_kernel<<<dim3((unsigned)blocks), dim3(256), 0, stream>>>(in, o, n);
  };
  cvt(x, xb, (size_t)S_LEN * HID);
  cvt(q_a_w, wcat, (size_t)QR * HID);
  cvt(kv_a_w, wcat + (size_t)QR * HID, (size_t)KVA_N * HID);
  hipMemsetAsync(wcat + (size_t)(QR + KVA_N) * HID, 0, (size_t)(KVAP - KVA_N) * HID * 2, stream);
  cvt(q_b_w, qbw, (size_t)Q_N * QR);
  cvt(kv_b_w, kvbw, (size_t)KV_N * KVR);
  cvt(o_w, ow, (size_t)HID * O_N);

  dim3 blk(256);
  // fused a-proj: qkv[S][1408] = x @ [q_a_w ‖ kv_a_w]^T  (352 blocks)
  gemm64<<<dim3(QKVA / 128, S_LEN / 64), blk, 0, stream>>>(xb, wcat, qkv, S_LEN, QKVA, HID);
  // rmsnorms -> bf16
  rmsnorm_kernel<<<dim3(S_LEN), blk, 0, stream>>>(qkv, q_a_ln, q_ln, QR, QKVA, QR);
  rmsnorm_kernel<<<dim3(S_LEN), blk, 0, stream>>>(qkv + QR, kv_a_ln, kv_ln, KVR, QKVA, KVR);
  // up-projections -> bf16
  gemm128<1><<<dim3(Q_N / 128, S_LEN / 128), blk, 0, stream>>>(q_ln, qbw, qbuf, S_LEN, Q_N, QR);
  gemm128<1><<<dim3(KV_N / 128, S_LEN / 128), blk, 0, stream>>>(kv_ln, kvbw, kvx, S_LEN, KV_N, KVR);
  // rope
  rope_table_kernel<<<dim3(S_LEN / 256), blk, 0, stream>>>(pos, ct, st);
  rope_q_kernel<<<dim3((S_LEN * NH + 255) / 256), blk, 0, stream>>>(qbuf, ct, st);
  rope_k_kernel<<<dim3(S_LEN / 256), blk, 0, stream>>>(qkv + QR + KVR, ct, st, kr);
  // per-head contiguous K and transposed V
  kc_build<<<dim3(NH * S_LEN * 32 / 256), blk, 0, stream>>>(kvx, kr, kcb);
  vtrans<<<dim3(S_LEN / 64, DV / 64, NH), blk, 0, stream>>>(kvx, vtg);
  // fused attention
  attn4<<<dim3(NH * S_LEN / 64), blk, 0, stream>>>(qbuf, kcb, vtg, ao);
  // output projection (fp32 out)
  gemm128<0><<<dim3(HID / 128, S_LEN / 128), blk, 0, stream>>>(ao, ow, out, S_LEN, HID, O_N);
}

// Round 6
// 534.006 us; speedup vs baseline: 1.2547x; 1.2289x over previous
//
#include <hip/hip_runtime.h>
#include <hip/hip_bf16.h>

#define HID 2048
#define NH 20
#define QR 768
#define KVR 512
#define DN 192
#define DR 64
#define DV 256
#define HD 256          // HEAD_DIM = DN + DR
#define S_LEN 2048
#define HKV 448         // DN + DV
#define KV_N (NH * HKV) // 8960
#define Q_N (NH * HD)   // 5120
#define O_N (NH * DV)   // 5120
#define KVA_N (KVR + DR) // 576
#define KVAP 640         // padded kv_a rows
#define QKVA (QR + KVAP) // 1408 fused a-proj cols

typedef short bf16x8 __attribute__((ext_vector_type(8)));
typedef short bf16x4 __attribute__((ext_vector_type(4)));
typedef float f32x4 __attribute__((ext_vector_type(4)));

__device__ inline short f2bs(float f) {
  __hip_bfloat16 h = __float2bfloat16(f);
  return *reinterpret_cast<short*>(&h);
}
__device__ inline float bs2f(short s) {
  __hip_bfloat16 h = *reinterpret_cast<__hip_bfloat16*>(&s);
  return __bfloat162float(h);
}

__device__ inline void gload16(const void* g, void* l) {
  __builtin_amdgcn_global_load_lds((const __attribute__((address_space(1))) void*)g,
                                   (__attribute__((address_space(3))) void*)l, 16, 0, 0);
}

#define WAIT_LGKM0() asm volatile("s_waitcnt lgkmcnt(0)" ::: "memory")
#define WAIT_VM0() asm volatile("s_waitcnt vmcnt(0)" ::: "memory")

// ---------------- fp32 -> bf16 convert ----------------
__global__ void f2b_kernel(const float* __restrict__ in, short* __restrict__ out, size_t n) {
  size_t i = (size_t)blockIdx.x * blockDim.x + threadIdx.x;
  size_t stride = (size_t)gridDim.x * blockDim.x;
  for (; i < n; i += stride) out[i] = f2bs(in[i]);
}

// ---------------- big GEMM: 128x128 tile, BK=64, global_load_lds + XOR swizzle ----------------
template <int OUT_BF16>
__global__ __launch_bounds__(256) void gemm128(const short* __restrict__ A,
                                               const short* __restrict__ B,
                                               void* __restrict__ Cp,
                                               int M, int N, int K) {
  __shared__ alignas(16) short As[128 * 64];
  __shared__ alignas(16) short Bs[128 * 64];
  int tid = threadIdx.x;
  int w = tid >> 6, l = tid & 63;
  int lr = l & 15, lg = l >> 4;
  int wr = w >> 1, wc = w & 1;
  int row0 = blockIdx.y * 128, col0 = blockIdx.x * 128;
  f32x4 acc[4][4] = {};
  for (int k0 = 0; k0 < K; k0 += 64) {
    if (k0) __syncthreads();
#pragma unroll
    for (int p = 0; p < 4; ++p) {
      int c = p * 256 + tid;
      int row = c >> 3;
      int sb = ((c & 7) * 16) ^ ((row & 7) << 4);
      gload16((const char*)A + ((size_t)(row0 + row) * K + k0) * 2 + sb, (char*)As + c * 16);
      gload16((const char*)B + ((size_t)(col0 + row) * K + k0) * 2 + sb, (char*)Bs + c * 16);
    }
    __syncthreads();
    bf16x8 af[4][2], bf[4][2];
#pragma unroll
    for (int m = 0; m < 4; ++m)
#pragma unroll
      for (int kk = 0; kk < 2; ++kk) {
        int ra = wr * 64 + m * 16 + lr;
        int rb = wc * 64 + m * 16 + lr;
        int cb = kk * 64 + lg * 16;
        af[m][kk] = *(const bf16x8*)((const char*)As + ra * 128 + (cb ^ ((ra & 7) << 4)));
        bf[m][kk] = *(const bf16x8*)((const char*)Bs + rb * 128 + (cb ^ ((rb & 7) << 4)));
      }
#pragma unroll
    for (int m = 0; m < 4; ++m)
#pragma unroll
      for (int n = 0; n < 4; ++n) {
        acc[m][n] = __builtin_amdgcn_mfma_f32_16x16x32_bf16(af[m][0], bf[n][0], acc[m][n], 0, 0, 0);
        acc[m][n] = __builtin_amdgcn_mfma_f32_16x16x32_bf16(af[m][1], bf[n][1], acc[m][n], 0, 0, 0);
      }
  }
#pragma unroll
  for (int m = 0; m < 4; ++m)
#pragma unroll
    for (int n = 0; n < 4; ++n)
#pragma unroll
      for (int r = 0; r < 4; ++r) {
        int row = row0 + wr * 64 + m * 16 + lg * 4 + r;
        int col = col0 + wc * 64 + n * 16 + lr;
        if (OUT_BF16)
          ((short*)Cp)[(size_t)row * N + col] = f2bs(acc[m][n][r]);
        else
          ((float*)Cp)[(size_t)row * N + col] = acc[m][n][r];
      }
}

// ---------------- medium GEMM: 64x128 tile (for wide-short shapes) ----------------
__global__ __launch_bounds__(256) void gemm64(const short* __restrict__ A,
                                              const short* __restrict__ B,
                                              float* __restrict__ C,
                                              int M, int N, int K) {
  __shared__ alignas(16) short As[64 * 64];    // 8KB
  __shared__ alignas(16) short Bs[128 * 64];   // 16KB
  int tid = threadIdx.x;
  int w = tid >> 6, l = tid & 63;
  int lr = l & 15, lg = l >> 4;
  int wr = w >> 1, wc = w & 1;
  int row0 = blockIdx.y * 64, col0 = blockIdx.x * 128;
  f32x4 acc[2][4] = {};
  for (int k0 = 0; k0 < K; k0 += 64) {
    if (k0) __syncthreads();
#pragma unroll
    for (int p = 0; p < 2; ++p) {
      int c = p * 256 + tid;
      int row = c >> 3;
      int sb = ((c & 7) * 16) ^ ((row & 7) << 4);
      gload16((const char*)A + ((size_t)(row0 + row) * K + k0) * 2 + sb, (char*)As + c * 16);
    }
#pragma unroll
    for (int p = 0; p < 4; ++p) {
      int c = p * 256 + tid;
      int row = c >> 3;
      int sb = ((c & 7) * 16) ^ ((row & 7) << 4);
      gload16((const char*)B + ((size_t)(col0 + row) * K + k0) * 2 + sb, (char*)Bs + c * 16);
    }
    __syncthreads();
    bf16x8 af[2][2], bf[4][2];
#pragma unroll
    for (int m = 0; m < 2; ++m)
#pragma unroll
      for (int kk = 0; kk < 2; ++kk) {
        int ra = wr * 32 + m * 16 + lr;
        int cb = kk * 64 + lg * 16;
        af[m][kk] = *(const bf16x8*)((const char*)As + ra * 128 + (cb ^ ((ra & 7) << 4)));
      }
#pragma unroll
    for (int n = 0; n < 4; ++n)
#pragma unroll
      for (int kk = 0; kk < 2; ++kk) {
        int rb = wc * 64 + n * 16 + lr;
        int cb = kk * 64 + lg * 16;
        bf[n][kk] = *(const bf16x8*)((const char*)Bs + rb * 128 + (cb ^ ((rb & 7) << 4)));
      }
#pragma unroll
    for (int m = 0; m < 2; ++m)
#pragma unroll
      for (int n = 0; n < 4; ++n) {
        acc[m][n] = __builtin_amdgcn_mfma_f32_16x16x32_bf16(af[m][0], bf[n][0], acc[m][n], 0, 0, 0);
        acc[m][n] = __builtin_amdgcn_mfma_f32_16x16x32_bf16(af[m][1], bf[n][1], acc[m][n], 0, 0, 0);
      }
  }
#pragma unroll
  for (int m = 0; m < 2; ++m)
#pragma unroll
    for (int n = 0; n < 4; ++n)
#pragma unroll
      for (int r = 0; r < 4; ++r) {
        int row = row0 + wr * 32 + m * 16 + lg * 4 + r;
        int col = col0 + wc * 64 + n * 16 + lr;
        C[(size_t)row * N + col] = acc[m][n][r];
      }
}

// ---------------- rmsnorm (fp32 in, bf16 out) ----------------
__global__ __launch_bounds__(256) void rmsnorm_kernel(const float* __restrict__ in,
                                                      const float* __restrict__ w,
                                                      short* __restrict__ out,
                                                      int N, int in_stride, int out_stride) {
  int row = blockIdx.x;
  const float* x = in + (size_t)row * in_stride;
  float ss = 0.f;
  for (int i = threadIdx.x; i < N; i += 256) { float v = x[i]; ss += v * v; }
#pragma unroll
  for (int off = 32; off >= 1; off >>= 1) ss += __shfl_down(ss, off);
  __shared__ float red[4];
  if ((threadIdx.x & 63) == 0) red[threadIdx.x >> 6] = ss;
  __syncthreads();
  float tot = red[0] + red[1] + red[2] + red[3];
  float sc = rsqrtf(tot / (float)N + 1e-5f);
  short* o = out + (size_t)row * out_stride;
  for (int i = threadIdx.x; i < N; i += 256) o[i] = f2bs(x[i] * sc * w[i]);
}

// ---------------- rope tables ----------------
__global__ void rope_table_kernel(const int* __restrict__ pos, float* __restrict__ ct,
                                  float* __restrict__ st) {
  int s = blockIdx.x * blockDim.x + threadIdx.x;
  if (s >= S_LEN) return;
  double p = (double)pos[s];
  for (int d = 0; d < 32; ++d) {
    double invf = exp(-((double)(2 * d) / 64.0) * log(1.0e6));
    double a = p * invf;
    ct[s * 32 + d] = (float)cos(a);
    st[s * 32 + d] = (float)sin(a);
  }
}

// ---------------- rope applied in-place to q's rope slice ----------------
__global__ void rope_q_kernel(short* __restrict__ q, const float* __restrict__ ct,
                              const float* __restrict__ st) {
  int idx = blockIdx.x * blockDim.x + threadIdx.x;
  if (idx >= S_LEN * NH) return;
  int s = idx / NH, h = idx % NH;
  short* p = q + (size_t)s * Q_N + h * HD + DN;
  float x[64];
#pragma unroll
  for (int i = 0; i < 64; ++i) x[i] = bs2f(p[i]);
  const float* c = ct + s * 32;
  const float* sn = st + s * 32;
#pragma unroll
  for (int d = 0; d < 32; ++d) {
    float x1 = x[2 * d], x2 = x[2 * d + 1];
    p[d] = f2bs(x1 * c[d] - x2 * sn[d]);
    p[32 + d] = f2bs(x1 * sn[d] + x2 * c[d]);
  }
}

// ---------------- rope for shared k_rope (reads fused qkv buffer) ----------------
__global__ void rope_k_kernel(const float* __restrict__ base, const float* __restrict__ ct,
                              const float* __restrict__ st, short* __restrict__ kr) {
  int s = blockIdx.x * blockDim.x + threadIdx.x;
  if (s >= S_LEN) return;
  const float* x = base + (size_t)s * QKVA;
  const float* c = ct + s * 32;
  const float* sn = st + s * 32;
  short* o = kr + s * 64;
#pragma unroll
  for (int d = 0; d < 32; ++d) {
    float x1 = x[2 * d], x2 = x[2 * d + 1];
    o[d] = f2bs(x1 * c[d] - x2 * sn[d]);
    o[32 + d] = f2bs(x1 * sn[d] + x2 * c[d]);
  }
}

// ---------------- build Kc[h][s][256] = k_nope ‖ roped k_rope ----------------
__global__ void kc_build(const short* __restrict__ kvx, const short* __restrict__ kr,
                         short* __restrict__ kc) {
  int idx = blockIdx.x * 256 + threadIdx.x;
  int h = idx >> 16;
  int r = idx & 65535;
  int s = r >> 5, c = r & 31;
  const short* src = (c < 24) ? kvx + (size_t)s * KV_N + h * HKV + c * 8
                              : kr + (size_t)s * 64 + (c - 24) * 8;
  *(bf16x8*)(kc + ((size_t)h * S_LEN + s) * HD + c * 8) = *(const bf16x8*)src;
}

// ---------------- transpose V: Vt[h][d][s] ----------------
__global__ __launch_bounds__(256) void vtrans(const short* __restrict__ kvx,
                                              short* __restrict__ vtg) {
  __shared__ short tile[64][65];
  int s0 = blockIdx.x * 64, d0 = blockIdx.y * 64, h = blockIdx.z;
  int tid = threadIdx.x;
#pragma unroll
  for (int p = 0; p < 2; ++p) {
    int s = p * 32 + (tid >> 3), dc = (tid & 7) * 8;
    bf16x8 v = *(const bf16x8*)(kvx + (size_t)(s0 + s) * KV_N + h * HKV + DN + d0 + dc);
#pragma unroll
    for (int j = 0; j < 8; ++j) tile[s][dc + j] = v[j];
  }
  __syncthreads();
#pragma unroll
  for (int p = 0; p < 2; ++p) {
    int d = p * 32 + (tid >> 3), sc = (tid & 7) * 8;
    bf16x8 o;
#pragma unroll
    for (int j = 0; j < 8; ++j) o[j] = tile[sc + j][d];
    *(bf16x8*)(vtg + ((size_t)h * DV + d0 + d) * S_LEN + s0 + sc) = o;
  }
}

// ---------------- fused flash attention v5: swapped QK^T, lane-local softmax ----------------
// grid = 640 (XCD-swizzled); 256 thr (4 waves x 16 q-rows); KVBLK=32
// S^T = mfma(K,Q): lane holds 8 scores of ONE q-row (q=lane&15) -> softmax is
// 7 in-lane max + 2 shuffles; P packs in-lane into the PV A-frag (no LDS round trip).
// V rows permuted to match P key order; K and V single-buffer LDS via gload_lds,
// both with 16B XOR-swizzled SOURCE. LDS = exactly 32KB; launch_bounds caps VGPR@128.
__global__ __launch_bounds__(256, 4) void attn5(const short* __restrict__ q,
                                                const short* __restrict__ kc,
                                                const short* __restrict__ vtg,
                                                short* __restrict__ out) {
  __shared__ alignas(16) short ks[32 * 256];   // 16KB, 512B rows, 3-bit src XOR
  __shared__ alignas(16) short vt[256 * 32];   // 16KB, vt[d][key], 64B rows, 2-bit src XOR
  int bid = blockIdx.x;
  int swz = (bid & 7) * 80 + (bid >> 3);
  int h = swz >> 5, qblk = swz & 31;
  int tid = threadIdx.x;
  int w = tid >> 6, l = tid & 63;
  int lr = l & 15, lg = l >> 4;

  const char* kch = (const char*)(kc + (size_t)h * S_LEN * HD);
  const short* vth = vtg + (size_t)h * DV * S_LEN;

  // Q frags (B operand now): lane lr = q-row, pre-scaled by 2^-4
  int qrow = qblk * 64 + w * 16 + lr;
  const short* qbase = q + (size_t)qrow * Q_N + h * HD;
  bf16x8 qf[8];
#pragma unroll
  for (int kk = 0; kk < 8; ++kk) {
    bf16x8 v = *(const bf16x8*)(qbase + kk * 32 + lg * 8);
#pragma unroll
    for (int j = 0; j < 8; ++j) v[j] = f2bs(bs2f(v[j]) * 0.0625f);
    qf[kk] = v;
  }

  f32x4 acc[16] = {};      // lane lr = d-col, rows lg*4+r = q-rows
  float m = -3e38f;        // running max for q = lr (this lane's row)
  float lsum = 0.f;        // running denom for q = lr

  for (int kb = 0; kb < S_LEN / 32; ++kb) {
    int key0 = kb * 32;
    // ---- stage K[32][256] and V^T[256][32] (gload_lds, swizzled source) ----
#pragma unroll
    for (int p = 0; p < 4; ++p) {
      int c = p * 256 + tid;
      int row = c >> 5;
      int sb = ((c & 31) * 16) ^ ((row & 7) << 4);
      gload16(kch + (size_t)(key0 + row) * 512 + sb, (char*)ks + c * 16);
    }
#pragma unroll
    for (int p = 0; p < 4; ++p) {
      int c = p * 256 + tid;
      int d = c >> 2, slot = c & 3;
      gload16(vth + (size_t)d * S_LEN + key0 + (slot ^ (d & 3)) * 8, (char*)vt + c * 16);
    }
    WAIT_VM0();
    __builtin_amdgcn_s_barrier();

    // ---- QK^T swapped: s0 rows = keys 0..15, s1 rows = keys 16..31; col = q ----
    f32x4 s0 = {}, s1 = {};
    __builtin_amdgcn_s_setprio(1);
#pragma unroll
    for (int kk = 0; kk < 8; ++kk) {
      int cb = kk * 64 + lg * 16;
      int sw = (lr & 7) << 4;
      bf16x8 k0 = *(const bf16x8*)((const char*)ks + lr * 512 + (cb ^ sw));
      bf16x8 k1 = *(const bf16x8*)((const char*)ks + (16 + lr) * 512 + (cb ^ sw));
      s0 = __builtin_amdgcn_mfma_f32_16x16x32_bf16(k0, qf[kk], s0, 0, 0, 0);
      s1 = __builtin_amdgcn_mfma_f32_16x16x32_bf16(k1, qf[kk], s1, 0, 0, 0);
    }
    __builtin_amdgcn_s_setprio(0);

    // ---- softmax (all 8 scores belong to q = lr) ----
    float mx = fmaxf(fmaxf(fmaxf(s0[0], s0[1]), fmaxf(s0[2], s0[3])),
                     fmaxf(fmaxf(s1[0], s1[1]), fmaxf(s1[2], s1[3])));
    mx = fmaxf(mx, __shfl_xor(mx, 16));
    mx = fmaxf(mx, __shfl_xor(mx, 32));
    bool grow = mx > m + 8.f;
    if (__any((int)grow)) {
      float mn = fmaxf(m, mx);
      float co = __expf(m - mn);
      m = mn;
      lsum *= co;
      // acc rows are q = lg*4+r -> fetch that row's co from a lane with lr == lg*4+r
      float c0 = __shfl(co, (l & 48) | (lg * 4 + 0));
      float c1 = __shfl(co, (l & 48) | (lg * 4 + 1));
      float c2 = __shfl(co, (l & 48) | (lg * 4 + 2));
      float c3 = __shfl(co, (l & 48) | (lg * 4 + 3));
#pragma unroll
      for (int t = 0; t < 16; ++t) {
        acc[t][0] *= c0; acc[t][1] *= c1; acc[t][2] *= c2; acc[t][3] *= c3;
      }
    }
    float e0 = __expf(s0[0] - m), e1 = __expf(s0[1] - m);
    float e2 = __expf(s0[2] - m), e3 = __expf(s0[3] - m);
    float e4 = __expf(s1[0] - m), e5 = __expf(s1[1] - m);
    float e6 = __expf(s1[2] - m), e7 = __expf(s1[3] - m);
    float ts = ((e0 + e1) + (e2 + e3)) + ((e4 + e5) + (e6 + e7));
    ts += __shfl_xor(ts, 16);
    ts += __shfl_xor(ts, 32);
    lsum += ts;
    bf16x8 pa;
    pa[0] = f2bs(e0); pa[1] = f2bs(e1); pa[2] = f2bs(e2); pa[3] = f2bs(e3);
    pa[4] = f2bs(e4); pa[5] = f2bs(e5); pa[6] = f2bs(e6); pa[7] = f2bs(e7);

    // ---- PV: acc[t] += P(A) * Vperm(B).  B lane lr = d = t*16+lr,
    //      keys: slots {lg>>1, (lg>>1)+2} XOR (d&3), half lg&1  ----
    __builtin_amdgcn_s_setprio(1);
#pragma unroll
    for (int t = 0; t < 16; ++t) {
      int d = t * 16 + lr;
      const char* vrow = (const char*)vt + d * 64 + (lg & 1) * 8;
      int dk = d & 3;
      bf16x4 lo = *(const bf16x4*)(vrow + (((lg >> 1) ^ dk) << 4));
      bf16x4 hi = *(const bf16x4*)(vrow + ((((lg >> 1) + 2) ^ dk) << 4));
      bf16x8 vf = __builtin_shufflevector(lo, hi, 0, 1, 2, 3, 4, 5, 6, 7);
      acc[t] = __builtin_amdgcn_mfma_f32_16x16x32_bf16(pa, vf, acc[t], 0, 0, 0);
    }
    __builtin_amdgcn_s_setprio(0);
    WAIT_LGKM0();
    __builtin_amdgcn_s_barrier();   // all waves done reading ks/vt
  }

  float inv = 1.f / lsum;  // valid for q = lr
  float i0 = __shfl(inv, (l & 48) | (lg * 4 + 0));
  float i1 = __shfl(inv, (l & 48) | (lg * 4 + 1));
  float i2 = __shfl(inv, (l & 48) | (lg * 4 + 2));
  float i3 = __shfl(inv, (l & 48) | (lg * 4 + 3));
#pragma unroll
  for (int t = 0; t < 16; ++t) {
    int row = qblk * 64 + w * 16 + lg * 4;
    int col = h * DV + t * 16 + lr;
    out[(size_t)(row + 0) * O_N + col] = f2bs(acc[t][0] * i0);
    out[(size_t)(row + 1) * O_N + col] = f2bs(acc[t][1] * i1);
    out[(size_t)(row + 2) * O_N + col] = f2bs(acc[t][2] * i2);
    out[(size_t)(row + 3) * O_N + col] = f2bs(acc[t][3] * i3);
  }
}

extern "C" void kernel_launch(void* const* d_in, const int* in_sizes, int n_in,
                              void* d_out, int out_size, void* d_ws, size_t ws_size,
                              hipStream_t stream) {
  const float* x       = (const float*)d_in[0];
  const int*   pos     = (const int*)d_in[1];
  const float* q_a_w   = (const float*)d_in[2];
  const float* q_b_w   = (const float*)d_in[3];
  const float* kv_a_w  = (const float*)d_in[4];
  const float* kv_b_w  = (const float*)d_in[5];
  const float* o_w     = (const float*)d_in[6];
  const float* q_a_ln  = (const float*)d_in[7];
  const float* kv_a_ln = (const float*)d_in[8];
  float* out = (float*)d_out;

  char* p = (char*)d_ws;
  auto alloc = [&](size_t bytes) {
    char* r = p;
    p += (bytes + 255) & ~(size_t)255;
    return r;
  };
  short* xb    = (short*)alloc((size_t)S_LEN * HID * 2);
  short* wcat  = (short*)alloc((size_t)QKVA * HID * 2);   // q_a_w ‖ kv_a_w(padded)
  short* qbw   = (short*)alloc((size_t)Q_N * QR * 2);
  short* kvbw  = (short*)alloc((size_t)KV_N * KVR * 2);
  short* ow    = (short*)alloc((size_t)HID * O_N * 2);
  float* qkv   = (float*)alloc((size_t)S_LEN * QKVA * 4); // fused a-proj out
  short* q_ln  = (short*)alloc((size_t)S_LEN * QR * 2);
  short* qbuf  = (short*)alloc((size_t)S_LEN * Q_N * 2);
  short* kv_ln = (short*)alloc((size_t)S_LEN * KVR * 2);
  short* kvx   = (short*)alloc((size_t)S_LEN * KV_N * 2);
  short* kr    = (short*)alloc((size_t)S_LEN * 64 * 2);
  float* ct    = (float*)alloc((size_t)S_LEN * 32 * 4);
  float* st    = (float*)alloc((size_t)S_LEN * 32 * 4);
  short* ao    = (short*)alloc((size_t)S_LEN * O_N * 2);
  short* kcb   = (short*)alloc((size_t)NH * S_LEN * HD * 2);
  short* vtg   = (short*)alloc((size_t)NH * DV * S_LEN * 2);
  (void)ws_size; (void)n_in; (void)in_sizes; (void)out_size;

  auto cvt = [&](const float* in, short* o, size_t n) {
    size_t blocks = (n + 255) / 256;
    if (blocks > 2048) blocks = 2048;
    f2b_kernel<<<dim3((unsigned)blocks), dim3(256), 0, stream>>>(in, o, n);
  };
  cvt(x, xb, (size_t)S_LEN * HID);
  cvt(q_a_w, wcat, (size_t)QR * HID);
  cvt(kv_a_w, wcat + (size_t)QR * HID, (size_t)KVA_N * HID);
  hipMemsetAsync(wcat + (size_t)(QR + KVA_N) * HID, 0, (size_t)(KVAP - KVA_N) * HID * 2, stream);
  cvt(q_b_w, qbw, (size_t)Q_N * QR);
  cvt(kv_b_w, kvbw, (size_t)KV_N * KVR);
  cvt(o_w, ow, (size_t)HID * O_N);

  dim3 blk(256);
  // fused a-proj: qkv[S][1408] = x @ [q_a_w ‖ kv_a_w]^T  (352 blocks)
  gemm64<<<dim3(QKVA / 128, S_LEN / 64), blk, 0, stream>>>(xb, wcat, qkv, S_LEN, QKVA, HID);
  // rmsnorms -> bf16
  rmsnorm_kernel<<<dim3(S_LEN), blk, 0, stream>>>(qkv, q_a_ln, q_ln, QR, QKVA, QR);
  rmsnorm_kernel<<<dim3(S_LEN), blk, 0, stream>>>(qkv + QR, kv_a_ln, kv_ln, KVR, QKVA, KVR);
  // up-projections -> bf16
  gemm128<1><<<dim3(Q_N / 128, S_LEN / 128), blk, 0, stream>>>(q_ln, qbw, qbuf, S_LEN, Q_N, QR);
  gemm128<1><<<dim3(KV_N / 128, S_LEN / 128), blk, 0, stream>>>(kv_ln, kvbw, kvx, S_LEN, KV_N, KVR);
  // rope
  rope_table_kernel<<<dim3(S_LEN / 256), blk, 0, stream>>>(pos, ct, st);
  rope_q_kernel<<<dim3((S_LEN * NH + 255) / 256), blk, 0, stream>>>(qbuf, ct, st);
  rope_k_kernel<<<dim3(S_LEN / 256), blk, 0, stream>>>(qkv + QR + KVR, ct, st, kr);
  // per-head contiguous K and transposed V
  kc_build<<<dim3(NH * S_LEN * 32 / 256), blk, 0, stream>>>(kvx, kr, kcb);
  vtrans<<<dim3(S_LEN / 64, DV / 64, NH), blk, 0, stream>>>(kvx, vtg);
  // fused attention
  attn5<<<dim3(NH * S_LEN / 64), blk, 0, stream>>>(qbuf, kcb, vtg, ao);
  // output projection (fp32 out)
  gemm128<0><<<dim3(HID / 128, S_LEN / 128), blk, 0, stream>>>(ao, ow, out, S_LEN, HID, O_N);
}